// Round 21
// baseline (35.094 us; speedup 1.0000x reference)
//
#include <hip/hip_runtime.h>

#define NB 32
#define TLEN 480000
#define NF 1876                    // frames per row
#define WPR 470                    // waves per row (block-ownership)
#define NWAVE (WPR * NB)           // 15040 = 8 * 1880
#define WTHREADS 256

// ---- pure-DPP full-wave reduction: 6 dpp v_add + 1 readlane, ZERO DS ops --
template <int CTRL>
__device__ __forceinline__ float dpp_add(float x) {
    int y = __builtin_amdgcn_update_dpp(0, __float_as_int(x), CTRL, 0xF, 0xF, true);
    return x + __int_as_float(y);
}

__device__ __forceinline__ float wave_reduce(float s) {
    s = dpp_add<0xB1>(s);    // quad_perm(1,0,3,2) : xor1
    s = dpp_add<0x4E>(s);    // quad_perm(2,3,0,1) : xor2
    s = dpp_add<0x124>(s);   // row_ror:4
    s = dpp_add<0x128>(s);   // row_ror:8
    s = dpp_add<0x142>(s);   // row_bcast15
    s = dpp_add<0x143>(s);   // row_bcast31 -> lane63 = full-wave total
    return __int_as_float(__builtin_amdgcn_readlane(__float_as_int(s), 63));
}

__device__ __forceinline__ float f4c(const float4& v, int j) {
    return j == 0 ? v.x : (j == 1 ? v.y : (j == 2 ? v.z : v.w));
}

// ---- kernel 1: block-ownership — each byte loaded ONCE (1.0x logical) ----
// Wave wv owns blocks g = 4wv-2+u (u=0..3), block g = samples [256g,256g+256).
// Block g feeds frames f = g+2-q (q=0..3, q = position of block in frame).
// Wave covers frames f = 4wv-3 .. 4wv+3 (7 bins, df = u-q+3).
// df<3  -> "hi" partial (frame owned by wave below), df>=3 -> "lo" partial.
// Frame f total = lo[f] (+ hi[f] if f%4 != 0). All indices compile-time.
__global__ __launch_bounds__(WTHREADS) void seg_frames(
    const float* __restrict__ est, const float* __restrict__ tgt,
    float* __restrict__ ws_lo, float* __restrict__ ws_hi,
    float* __restrict__ ws_bs)
{
    const int tid  = threadIdx.x;
    const int lane = tid & 63;
    const int wave = tid >> 6;

    // XCD-aware swizzle: XCD k owns contiguous wave range (15040 = 8*1880)
    const int gw0 = (blockIdx.x & 7) * (NWAVE / 8) + (blockIdx.x >> 3) * 4;
    const int gw  = gw0 + wave;
    const int b   = gw / WPR;
    const int wv  = gw % WPR;

    const float* erow = est + (size_t)b * TLEN;
    const float* trow = tgt + (size_t)b * TLEN;

    // w2(q, x=4*lane+j): quarter-turn rotation -> 2 trans ops per j (8 total)
    float w2v[4][4];
#pragma unroll
    for (int j = 0; j < 4; ++j) {
        float ang = (6.28318530717958647692f / 1024.0f) * (float)(4 * lane + j);
        float c = __cosf(ang), s = __sinf(ang);
        float w0 = 0.5f - 0.5f * c;
        float w1 = 0.5f + 0.5f * s;
        float w2_ = 0.5f + 0.5f * c;
        float w3 = 0.5f - 0.5f * s;
        w2v[0][j] = w0 * w0;
        w2v[1][j] = w1 * w1;
        w2v[2][j] = w2_ * w2_;
        w2v[3][j] = w3 * w3;
    }

    float acc[7][5];
#pragma unroll
    for (int df = 0; df < 7; ++df)
#pragma unroll
        for (int s5 = 0; s5 < 5; ++s5) acc[df][s5] = 0.f;

    float pe = 0.f, pt = 0.f;      // plain sums over owned REAL samples

    if (wv >= 1 && wv <= 468) {
        // ================= fast path: 8 loads, all owned blocks real ======
        const float4* e4 = (const float4*)erow;
        const float4* t4 = (const float4*)trow;

        float4 E[4], T[4];
#pragma unroll
        for (int u = 0; u < 4; ++u) {
            int g4 = 64 * (4 * wv - 2 + u) + lane;
            E[u] = e4[g4];
            T[u] = t4[g4];
        }
        __builtin_amdgcn_sched_barrier(0);   // pin loads above

#pragma unroll
        for (int u = 0; u < 4; ++u) {
            float4 ev4 = E[u], tv4 = T[u];
#pragma unroll
            for (int j = 0; j < 4; ++j) {
                float e = f4c(ev4, j), t = f4c(tv4, j);
                float et = e * t, tt2 = t * t, ee2 = e * e;
#pragma unroll
                for (int q = 0; q < 4; ++q) {
                    const int df = u - q + 3;      // 0..6, compile-time
                    float w2 = w2v[q][j];
                    acc[df][0] = fmaf(w2, et,  acc[df][0]);
                    acc[df][1] = fmaf(w2, tt2, acc[df][1]);
                    acc[df][2] = fmaf(w2, ee2, acc[df][2]);
                    acc[df][3] = fmaf(w2, e,   acc[df][3]);
                    acc[df][4] = fmaf(w2, t,   acc[df][4]);
                }
            }
            // all 4 owned blocks are real samples -> mean partials
            pe += (ev4.x + ev4.y) + (ev4.z + ev4.w);
            pt += (tv4.x + tv4.y) + (tv4.z + tv4.w);
        }
    } else {
        // ================= edge path (wv==0 or wv==469): reflect ==========
#pragma unroll
        for (int u = 0; u < 4; ++u) {
            int g = 4 * wv - 2 + u;
            bool ownmean = (wv == 0) ? (u >= 2) : (u == 0);  // real owned blocks
#pragma unroll
            for (int j = 0; j < 4; ++j) {
                int s = 256 * g + 4 * lane + j;
                int idx = s < 0 ? -s : (s >= TLEN ? 2 * (TLEN - 1) - s : s);
                float e = erow[idx], t = trow[idx];
                float et = e * t, tt2 = t * t, ee2 = e * e;
#pragma unroll
                for (int q = 0; q < 4; ++q) {
                    const int df = u - q + 3;
                    float w2 = w2v[q][j];
                    acc[df][0] = fmaf(w2, et,  acc[df][0]);
                    acc[df][1] = fmaf(w2, tt2, acc[df][1]);
                    acc[df][2] = fmaf(w2, ee2, acc[df][2]);
                    acc[df][3] = fmaf(w2, e,   acc[df][3]);
                    acc[df][4] = fmaf(w2, t,   acc[df][4]);
                }
                if (ownmean) { pe += e; pt += t; }
            }
        }
    }

    // ---- reduce + store the 7 frame-partials (lo for df>=3, hi for df<3) --
#pragma unroll
    for (int df = 0; df < 7; ++df) {
        const int f = 4 * wv + df - 3;           // wave-uniform
        if (f >= 0 && f < NF) {
            float r0 = wave_reduce(acc[df][0]);
            float r1 = wave_reduce(acc[df][1]);
            float r2 = wave_reduce(acc[df][2]);
            float r3 = wave_reduce(acc[df][3]);
            float r4 = wave_reduce(acc[df][4]);
            float v = r0;
            v = (lane == 1) ? r1 : v;
            v = (lane == 2) ? r2 : v;
            v = (lane == 3) ? r3 : v;
            v = (lane == 4) ? r4 : v;
            float* dst = (df < 3 ? ws_hi : ws_lo) + (size_t)(b * NF + f) * 5;
            if (lane < 5) dst[lane] = v;
        }
    }

    // per-wave mean partials -> workspace
    pe = wave_reduce(pe);
    pt = wave_reduce(pt);
    if (lane == 0) {
        ws_bs[(0 * NB + b) * WPR + wv] = pe;
        ws_bs[(1 * NB + b) * WPR + wv] = pt;
    }
}

// ------ kernel 2: row means + combine lo/hi partials -> loss --------------
__global__ __launch_bounds__(WTHREADS) void seg_final(
    const float* __restrict__ ws_lo, const float* __restrict__ ws_hi,
    const float* __restrict__ ws_bs, float* __restrict__ out)
{
    const int tid  = threadIdx.x;
    const int lane = tid & 63;
    const int wave = tid >> 6;
    const int idx0 = blockIdx.x * WTHREADS;

    int b0 = idx0 / NF;
    int ilast = idx0 + WTHREADS - 1;
    if (ilast > NB * NF - 1) ilast = NB * NF - 1;
    int b1 = ilast / NF;

    __shared__ float smean[4];   // [which*2 + sig]
    {
        int sig = wave & 1;
        int row = (wave >> 1) ? b1 : b0;
        const float* pbs = ws_bs + (size_t)(sig * NB + row) * WPR;
        float s = 0.f;
        for (int c = lane; c < WPR; c += 64) s += pbs[c];   // 8 iters, L2-hot
        s = wave_reduce(s);
        if (lane == 0) smean[wave] = s * (1.0f / (float)TLEN);
    }
    __syncthreads();

    int idx = idx0 + tid;
    if (idx >= NB * NF) return;
    int b = idx / NF;
    int f = idx - b * NF;
    int which = (b == b0) ? 0 : 1;
    float me = smean[which * 2 + 0];
    float mt = smean[which * 2 + 1];

    const float* plo = ws_lo + (size_t)idx * 5;
    const float* phi = ws_hi + (size_t)idx * 5;
    bool two = (f & 3) != 0;         // r!=0 frames have a second contributor
    float S_et = plo[0] + (two ? phi[0] : 0.f);
    float S_tt = plo[1] + (two ? phi[1] : 0.f);
    float S_ee = plo[2] + (two ? phi[2] : 0.f);
    float S_e  = plo[3] + (two ? phi[3] : 0.f);
    float S_t  = plo[4] + (two ? phi[4] : 0.f);
    const float W2 = 384.0f;         // sum of squared periodic Hann, exact

    float dot = S_et - mt * S_e - me * S_t + me * mt * W2;
    float tt  = S_tt - 2.0f * mt * S_t + mt * mt * W2;
    float ee  = S_ee - 2.0f * me * S_e + me * me * W2;

    float a     = dot / (tt + 1e-8f);
    float st2   = a * a * tt;
    float en2   = ee - 2.0f * a * dot + st2;
    float ratio = st2 / (en2 + 1e-8f);
    out[idx] = -10.0f * log10f(ratio + 1e-8f);
}

extern "C" void kernel_launch(void* const* d_in, const int* in_sizes, int n_in,
                              void* d_out, int out_size, void* d_ws, size_t ws_size,
                              hipStream_t stream)
{
    const float* est = (const float*)d_in[0];
    const float* tgt = (const float*)d_in[1];
    float* out = (float*)d_out;

    float* ws    = (float*)d_ws;
    float* ws_lo = ws;                                     // NB*NF*5   floats
    float* ws_hi = ws_lo + (size_t)NB * NF * 5;            // NB*NF*5   floats
    float* ws_bs = ws_hi + (size_t)NB * NF * 5;            // 2*NB*WPR  floats

    seg_frames<<<NWAVE / 4, WTHREADS, 0, stream>>>(est, tgt, ws_lo, ws_hi, ws_bs);
    dim3 grid2((NB * NF + WTHREADS - 1) / WTHREADS);
    seg_final<<<grid2, WTHREADS, 0, stream>>>(ws_lo, ws_hi, ws_bs, out);
}

// Round 22
// 32.764 us; speedup vs baseline: 1.0711x; 1.0711x over previous
//
#include <hip/hip_runtime.h>

#define NB 32
#define TLEN 480000
#define NF 1876                    // (480000 + 2*512 - 1024)/256 + 1
#define FR 4                       // frames per wave
#define WPR 469                    // ceil(NF/FR) waves per row
#define NWAVE (WPR * NB)           // 15008 = 8 XCDs * 1876
#define WTHREADS 256               // block size

typedef float v2f __attribute__((ext_vector_type(2)));

// ---- pure-DPP full-wave reduction: 6 dpp v_add + 1 readlane, ZERO DS ops --
template <int CTRL>
__device__ __forceinline__ float dpp_add(float x) {
    int y = __builtin_amdgcn_update_dpp(0, __float_as_int(x), CTRL, 0xF, 0xF, true);
    return x + __int_as_float(y);
}

__device__ __forceinline__ float wave_reduce(float s) {
    s = dpp_add<0xB1>(s);    // quad_perm(1,0,3,2) : xor1
    s = dpp_add<0x4E>(s);    // quad_perm(2,3,0,1) : xor2
    s = dpp_add<0x124>(s);   // row_ror:4
    s = dpp_add<0x128>(s);   // row_ror:8  -> each row-of-16 has its row sum
    s = dpp_add<0x142>(s);   // row_bcast15: row1 += r0 ; row3 += r2 (old vals)
    s = dpp_add<0x143>(s);   // row_bcast31: rows2-3 += (r0+r1) -> lane63 = total
    return __int_as_float(__builtin_amdgcn_readlane(__float_as_int(s), 63));
}

// ---- kernel 1: XCD swizzle + packed FP32 core, DS-free reductions --------
__global__ __launch_bounds__(WTHREADS) void seg_frames(
    const float* __restrict__ est, const float* __restrict__ tgt,
    float* __restrict__ ws_part, float* __restrict__ ws_bs)
{
    const int tid  = threadIdx.x;
    const int lane = tid & 63;
    const int wave = tid >> 6;

    // XCD-aware swizzle: XCD k owns contiguous wave range (halo L2 locality)
    const int gw0 = (blockIdx.x & 7) * (NWAVE / 8) + (blockIdx.x >> 3) * 4;
    const int gw  = gw0 + wave;
    const int b   = gw / WPR;
    const int wv  = gw % WPR;
    const int fb  = wv * FR;

    const float* erow = est + (size_t)b * TLEN;
    const float* trow = tgt + (size_t)b * TLEN;

    // squared window w2(q, x=4*lane+j): p = 256q + x; quarter-turn rotation
    // -> only cos/sin of θ(x): 8 trans ops. w2 = w*w packed by j-pairs.
    v2f w2p[4][2];
#pragma unroll
    for (int j = 0; j < 4; ++j) {
        float ang = (6.28318530717958647692f / 1024.0f) * (float)(4 * lane + j);
        float c = __cosf(ang), s = __sinf(ang);
        float w0 = 0.5f - 0.5f * c;
        float w1 = 0.5f + 0.5f * s;
        float w2_ = 0.5f + 0.5f * c;
        float w3 = 0.5f - 0.5f * s;
        w2p[0][j >> 1][j & 1] = w0 * w0;
        w2p[1][j >> 1][j & 1] = w1 * w1;
        w2p[2][j >> 1][j & 1] = w2_ * w2_;
        w2p[3][j >> 1][j & 1] = w3 * w3;
    }

    v2f pe2 = {0.f, 0.f}, pt2 = {0.f, 0.f};   // packed mean partials

    if (fb >= 4 && fb <= 1868) {
        // ================= fast path =================
        const float4* e4 = (const float4*)erow;
        const float4* t4 = (const float4*)trow;

        // issue ALL 14 loads up front — fully independent, max MLP
        float4 E[7], T[7];
#pragma unroll
        for (int m = 0; m < 7; ++m) {
            int g = 64 * (fb + m) - 128 + lane;
            E[m] = e4[g];
            T[m] = t4[g];
        }
        __builtin_amdgcn_sched_barrier(0);   // pin loads above

        // hop-major packed accumulators for 4 frames x 5 sums
        v2f acc[4][5];
#pragma unroll
        for (int i = 0; i < 4; ++i)
#pragma unroll
            for (int s5 = 0; s5 < 5; ++s5) acc[i][s5] = v2f{0.f, 0.f};

#pragma unroll
        for (int m = 0; m < 7; ++m) {
            float4 ev4 = E[m], tv4 = T[m];
#pragma unroll
            for (int jp = 0; jp < 2; ++jp) {
                v2f e = jp ? v2f{ev4.z, ev4.w} : v2f{ev4.x, ev4.y};
                v2f t = jp ? v2f{tv4.z, tv4.w} : v2f{tv4.x, tv4.y};
                v2f et = e * t, tt2 = t * t, ee2 = e * e;   // v_pk_mul_f32
#pragma unroll
                for (int i = 0; i < 4; ++i) {
                    if (m - i < 0 || m - i > 3) continue;   // const-folds
                    v2f w2 = w2p[m - i][jp];
                    acc[i][0] = __builtin_elementwise_fma(w2, et,  acc[i][0]);
                    acc[i][1] = __builtin_elementwise_fma(w2, tt2, acc[i][1]);
                    acc[i][2] = __builtin_elementwise_fma(w2, ee2, acc[i][2]);
                    acc[i][3] = __builtin_elementwise_fma(w2, e,   acc[i][3]);
                    acc[i][4] = __builtin_elementwise_fma(w2, t,   acc[i][4]);
                }
                if (m < 4) {       // owned samples [256fb-512, 256fb+511]
                    pe2 += e;      // v_pk_add_f32
                    pt2 += t;
                }
            }
        }

#pragma unroll
        for (int i = 0; i < 4; ++i) {
            float s0 = wave_reduce(acc[i][0].x + acc[i][0].y);
            float s1 = wave_reduce(acc[i][1].x + acc[i][1].y);
            float s2 = wave_reduce(acc[i][2].x + acc[i][2].y);
            float s3 = wave_reduce(acc[i][3].x + acc[i][3].y);
            float s4 = wave_reduce(acc[i][4].x + acc[i][4].y);
            if (lane == 0) {
                float* p = ws_part + (size_t)(b * NF + fb + i) * 5;
                p[0] = s0; p[1] = s1; p[2] = s2; p[3] = s3; p[4] = s4;
            }
        }
    } else {
        // ================= edge path (fb==0 or fb==1872) =================
        int nfr = NF - fb;
        if (nfr > FR) nfr = FR;

        for (int i = 0; i < nfr; ++i) {
            int f = fb + i;
            float s_et = 0.f, s_tt = 0.f, s_ee = 0.f, s_e = 0.f, s_t = 0.f;
#pragma unroll
            for (int q = 0; q < 4; ++q)
#pragma unroll
                for (int j = 0; j < 4; ++j) {
                    int s = 256 * f - 512 + 256 * q + 4 * lane + j;
                    int idx = s < 0 ? -s : (s >= TLEN ? 2 * (TLEN - 1) - s : s);
                    float ev = erow[idx], tv = trow[idx];
                    float w2 = w2p[q][j >> 1][j & 1];
                    float et = ev * tv;
                    s_et = fmaf(w2, et,      s_et);
                    s_tt = fmaf(w2, tv * tv, s_tt);
                    s_ee = fmaf(w2, ev * ev, s_ee);
                    s_e  = fmaf(w2, ev, s_e);
                    s_t  = fmaf(w2, tv, s_t);
                }
            s_et = wave_reduce(s_et);
            s_tt = wave_reduce(s_tt);
            s_ee = wave_reduce(s_ee);
            s_e  = wave_reduce(s_e);
            s_t  = wave_reduce(s_t);
            if (lane == 0) {
                float* p = ws_part + (size_t)(b * NF + f) * 5;
                p[0] = s_et; p[1] = s_tt; p[2] = s_ee; p[3] = s_e; p[4] = s_t;
            }
        }

        // owned samples for the means (disjoint from fast waves' coverage)
        const float4* e4 = (const float4*)erow;
        const float4* t4 = (const float4*)trow;
        if (fb == 0) {
            // own [0, 512): 128 float4, 2 per lane
#pragma unroll
            for (int k = 0; k < 2; ++k) {
                float4 ev4 = e4[lane + 64 * k];
                float4 tv4 = t4[lane + 64 * k];
                pe2 += v2f{ev4.x, ev4.y} + v2f{ev4.z, ev4.w};
                pt2 += v2f{tv4.x, tv4.y} + v2f{tv4.z, tv4.w};
            }
        } else {
            // own [478720, 480000): 320 float4, 5 per lane
#pragma unroll
            for (int k = 0; k < 5; ++k) {
                int g = 119680 + lane + 64 * k;
                float4 ev4 = e4[g];
                float4 tv4 = t4[g];
                pe2 += v2f{ev4.x, ev4.y} + v2f{ev4.z, ev4.w};
                pt2 += v2f{tv4.x, tv4.y} + v2f{tv4.z, tv4.w};
            }
        }
    }

    // per-wave plain-sum partials -> workspace (for the row means)
    float pe = wave_reduce(pe2.x + pe2.y);
    float pt = wave_reduce(pt2.x + pt2.y);
    if (lane == 0) {
        ws_bs[(0 * NB + b) * WPR + wv] = pe;
        ws_bs[(1 * NB + b) * WPR + wv] = pt;
    }
}

// ------ kernel 2 (fused): recompute row means per block + final loss ------
__global__ __launch_bounds__(WTHREADS) void seg_final(
    const float* __restrict__ ws_part, const float* __restrict__ ws_bs,
    float* __restrict__ out)
{
    const int tid  = threadIdx.x;
    const int lane = tid & 63;
    const int wave = tid >> 6;
    const int idx0 = blockIdx.x * WTHREADS;

    // block spans at most 2 batch rows; 4 waves reduce (sig in {e,t}) x {b0,b1}
    int b0 = idx0 / NF;
    int ilast = idx0 + WTHREADS - 1;
    if (ilast > NB * NF - 1) ilast = NB * NF - 1;
    int b1 = ilast / NF;

    __shared__ float smean[4];   // [which*2 + sig]
    {
        int sig = wave & 1;
        int row = (wave >> 1) ? b1 : b0;
        const float* pbs = ws_bs + (size_t)(sig * NB + row) * WPR;
        float s = 0.f;
        for (int c = lane; c < WPR; c += 64) s += pbs[c];   // 8 iters, L2-hot
        s = wave_reduce(s);
        if (lane == 0) smean[wave] = s * (1.0f / (float)TLEN);
    }
    __syncthreads();

    int idx = idx0 + tid;
    if (idx >= NB * NF) return;
    int b = idx / NF;
    int which = (b == b0) ? 0 : 1;
    float me = smean[which * 2 + 0];
    float mt = smean[which * 2 + 1];

    const float* p = ws_part + (size_t)idx * 5;
    float S_et = p[0], S_tt = p[1], S_ee = p[2], S_e = p[3], S_t = p[4];
    const float W2 = 384.0f;         // sum of squared periodic Hann, exact

    float dot = S_et - mt * S_e - me * S_t + me * mt * W2;
    float tt  = S_tt - 2.0f * mt * S_t + mt * mt * W2;
    float ee  = S_ee - 2.0f * me * S_e + me * me * W2;

    float a     = dot / (tt + 1e-8f);
    float st2   = a * a * tt;
    float en2   = ee - 2.0f * a * dot + st2;
    float ratio = st2 / (en2 + 1e-8f);
    out[idx] = -10.0f * log10f(ratio + 1e-8f);
}

extern "C" void kernel_launch(void* const* d_in, const int* in_sizes, int n_in,
                              void* d_out, int out_size, void* d_ws, size_t ws_size,
                              hipStream_t stream)
{
    const float* est = (const float*)d_in[0];
    const float* tgt = (const float*)d_in[1];
    float* out = (float*)d_out;

    float* ws      = (float*)d_ws;
    float* ws_part = ws;                                   // NB*NF*5   floats
    float* ws_bs   = ws_part + (size_t)NB * NF * 5;        // 2*NB*WPR  floats

    seg_frames<<<NWAVE / 4, WTHREADS, 0, stream>>>(est, tgt, ws_part, ws_bs);
    dim3 grid2((NB * NF + WTHREADS - 1) / WTHREADS);
    seg_final<<<grid2, WTHREADS, 0, stream>>>(ws_part, ws_bs, out);
}